// Round 2
// baseline (527.698 us; speedup 1.0000x reference)
//
#include <hip/hip_runtime.h>
#include <math.h>

#define NCOLS 4096
#define MROWS 4096
#define NLAYERS 5
#define RPB 16               // rows per block
#define NBLK (MROWS / RPB)   // 256 blocks == 256 CUs; all co-resident
#define TPB 512

__device__ __forceinline__ float sigf(float x) { return 1.0f / (1.0f + expf(-x)); }

// bf16 (packed in 32-bit words) -> float, exact
__device__ __forceinline__ float lo16(unsigned w) { return __uint_as_float(w << 16); }
__device__ __forceinline__ float hi16(unsigned w) { return __uint_as_float(w & 0xFFFF0000u); }

// float -> bf16 bits, round-to-nearest-even (A has no NaN/Inf)
__device__ __forceinline__ unsigned f2bf(float f) {
    unsigned u = __float_as_uint(f);
    return (u + 0x7FFFu + ((u >> 16) & 1u)) >> 16;
}

__device__ __forceinline__ void unpack8(uint4 w, float* a) {
    a[0] = lo16(w.x); a[1] = hi16(w.x); a[2] = lo16(w.y); a[3] = hi16(w.y);
    a[4] = lo16(w.z); a[5] = hi16(w.z); a[6] = lo16(w.w); a[7] = hi16(w.w);
}

// butterfly reductions, result broadcast to all 64 lanes
__device__ __forceinline__ float waveSum(float v) {
#pragma unroll
    for (int o = 32; o; o >>= 1) v += __shfl_xor(v, o, 64);
    return v;
}
__device__ __forceinline__ float waveMax(float v) {
#pragma unroll
    for (int o = 32; o; o >>= 1) v = fmaxf(v, __shfl_xor(v, o, 64));
    return v;
}

// grid barrier: all NBLK blocks co-resident (2048 waves << 8192 capacity).
// release on arrive (flushes this XCD's L2), acquire on observe (invalidates).
// Bail-out so a protocol bug fails the check instead of hanging the harness.
__device__ __forceinline__ void gbar(unsigned* bar, int slot) {
    __syncthreads();
    if (threadIdx.x == 0) {
        __hip_atomic_fetch_add(&bar[slot], 1u, __ATOMIC_ACQ_REL,
                               __HIP_MEMORY_SCOPE_AGENT);
        int spins = 0;
        while (__hip_atomic_load(&bar[slot], __ATOMIC_ACQUIRE,
                                 __HIP_MEMORY_SCOPE_AGENT) < (unsigned)NBLK) {
            __builtin_amdgcn_s_sleep(1);
            if (++spins > 5000000) break;  // ~150ms: fail loudly, don't hang
        }
    }
    __syncthreads();
}

// ONE persistent kernel. Block s owns rows [s*16, s*16+16) of A -- held in
// registers (bf16-packed, 64 VGPR) for the whole algorithm -- and owns cols
// [s*16, s*16+16) for the column-space (stage-2) phases, whose scalar state
// (r, x, b, one_l) lives in owner-thread registers across all 5 layers.
__global__ __launch_bounds__(TPB) void k_persist(
    const float* __restrict__ A, const float* __restrict__ theta_g,
    const float* __restrict__ theta_b, const float* __restrict__ fptr,
    const float* __restrict__ h, const float* __restrict__ thql,
    const float* __restrict__ thqr, float* __restrict__ bvec,
    float* __restrict__ rot, float* __restrict__ hwv, float* __restrict__ p1,
    float* __restrict__ p2, unsigned* __restrict__ bar, float* __restrict__ out) {
    __shared__ float prt[RPB][TPB];  // 32 KB reduction scratch (reused per phase)
    __shared__ float s_oner[RPB], s_rm[RPB], s_y[RPB], s_ro[RPB];
    __shared__ float s_ydl[RPB], s_ydrol[RPB];

    const int t = threadIdx.x, s = blockIdx.x, r0 = s * RPB;
    const int wid = t >> 6, lane = t & 63;
    // column-owner layout for stage-2 phases: col j = s*16 + c, group g of 32
    const int c = t & 15, g = t >> 4;
    const int j = s * 16 + c;
    float* smA = &prt[0][0];  // 512 floats
    float* smB = &prt[1][0];  // 512 floats

    uint4 w[RPB];  // the block's 16 rows of A, bf16-packed: 64 VGPRs, persistent
    float r_own = 0.f, x_own = 0.f, b_own = 0.f, onel_own = 0.f;

    // ================= P0: the ONLY read of A (fp32, 64 MB) =================
    {
        const float4* a4 = reinterpret_cast<const float4*>(A);
#pragma unroll
        for (int i = 0; i < RPB; i++) {
            size_t base = (size_t)(r0 + i) * 1024 + 2 * t;
            float4 fA = a4[base];
            float4 fB = a4[base + 1];
            prt[i][t] =
                ((fA.x + fA.y) + (fA.z + fA.w)) + ((fB.x + fB.y) + (fB.z + fB.w));
            uint4 u;
            u.x = f2bf(fA.x) | (f2bf(fA.y) << 16);
            u.y = f2bf(fA.z) | (f2bf(fA.w) << 16);
            u.z = f2bf(fB.x) | (f2bf(fB.y) << 16);
            u.w = f2bf(fB.z) | (f2bf(fB.w) << 16);
            w[i] = u;
        }
        __syncthreads();
#pragma unroll
        for (int rr = 0; rr < 2; rr++) {  // 2 rows per wave: rowsum -> right_mask
            int row = wid * 2 + rr;
            float sv = 0.f;
#pragma unroll
            for (int k = 0; k < 8; k++) sv += prt[row][lane + 64 * k];
            sv = waveSum(sv);
            if (lane == 0) {
                float q = 0.f;
#pragma unroll
                for (int k = 0; k < 4; k++)
                    q += sigf(thqr[2 * k] * sv + thqr[2 * k + 1]);
                float rmv = q * 0.25f;
                s_rm[row] = rmv;
                s_oner[row] = 1.0f - rmv;
                s_y[row] = 0.f;
            }
        }
        __syncthreads();
        float cs[8], cm[8];
#pragma unroll
        for (int cc = 0; cc < 8; cc++) { cs[cc] = 0.f; cm[cc] = -INFINITY; }
#pragma unroll
        for (int i = 0; i < RPB; i++) {
            float a[8];
            unpack8(w[i], a);
            float vi = s_rm[i];
#pragma unroll
            for (int cc = 0; cc < 8; cc++) {
                cs[cc] += a[cc];
                cm[cc] = fmaxf(cm[cc], a[cc] * vi);
            }
        }
        float4* q1 = reinterpret_cast<float4*>(p1 + (size_t)s * NCOLS + 8 * t);
        float4* q2 = reinterpret_cast<float4*>(p2 + (size_t)s * NCOLS + 8 * t);
        q1[0] = make_float4(cs[0], cs[1], cs[2], cs[3]);
        q1[1] = make_float4(cs[4], cs[5], cs[6], cs[7]);
        q2[0] = make_float4(cm[0], cm[1], cm[2], cm[3]);
        q2[1] = make_float4(cm[4], cm[5], cm[6], cm[7]);
    }
    gbar(bar, 0);

    // ================= S0: k_left (col init), owner = thread c, g==0 ========
    {
        float cs = 0.f, cm = -INFINITY;
#pragma unroll
        for (int k = 0; k < 8; k++) {
            int sp = g * 8 + k;
            cs += p1[(size_t)sp * NCOLS + j];
            cm = fmaxf(cm, p2[(size_t)sp * NCOLS + j]);
        }
        smA[t] = cs;
        smB[t] = cm;
        __syncthreads();
        if (g == 0) {
#pragma unroll
            for (int gg = 1; gg < 32; gg++) {
                cs += smA[gg * 16 + c];
                cm = fmaxf(cm, smB[gg * 16 + c]);
            }
            float q = 0.f;
#pragma unroll
            for (int k = 0; k < 4; k++) q += sigf(thql[2 * k] * cs + thql[2 * k + 1]);
            float lm = fmaxf(q * 0.25f, cm);
            onel_own = 1.0f - lm;
            hwv[j] = h[j] * lm / cs;
            r_own = fptr[0];
            x_own = 0.f;
            b_own = 1.0f;
            bvec[j] = 1.0f;
        }
    }
    gbar(bar, 1);

    // ================= layers =================
    for (int l = 0; l < NLAYERS; l++) {
        const int fin = (l == NLAYERS - 1);
        const float* tg = theta_g + l * 48;
        const float* tb = theta_b + l * 64;
        const int base = 2 + l * 4;

        // ---- P1: ro = (A@b)*one_r  +  colmax(A^T, ro) partials ----
        {
            const float4* b4 = reinterpret_cast<const float4*>(bvec);
            float4 bA = b4[2 * t];
            float4 bB = b4[2 * t + 1];
            float bb[8] = {bA.x, bA.y, bA.z, bA.w, bB.x, bB.y, bB.z, bB.w};
#pragma unroll
            for (int i = 0; i < RPB; i++) {
                float a[8];
                unpack8(w[i], a);
                float d = 0.f;
#pragma unroll
                for (int cc = 0; cc < 8; cc++) d += a[cc] * bb[cc];
                prt[i][t] = d;
            }
            __syncthreads();
#pragma unroll
            for (int rr = 0; rr < 2; rr++) {
                int row = wid * 2 + rr;
                float sv = 0.f;
#pragma unroll
                for (int k = 0; k < 8; k++) sv += prt[row][lane + 64 * k];
                sv = waveSum(sv);
                if (lane == 0) s_ro[row] = sv * s_oner[row];
            }
            __syncthreads();
            float cm[8];
#pragma unroll
            for (int cc = 0; cc < 8; cc++) cm[cc] = -INFINITY;
#pragma unroll
            for (int i = 0; i < RPB; i++) {
                float a[8];
                unpack8(w[i], a);
                float vi = s_ro[i];
#pragma unroll
                for (int cc = 0; cc < 8; cc++) cm[cc] = fmaxf(cm[cc], a[cc] * vi);
            }
            float4* q1 = reinterpret_cast<float4*>(p1 + (size_t)s * NCOLS + 8 * t);
            q1[0] = make_float4(cm[0], cm[1], cm[2], cm[3]);
            q1[1] = make_float4(cm[4], cm[5], cm[6], cm[7]);
        }
        gbar(bar, base + 0);

        // ---- S1: ro_t[j] = max over splits * one_l ----
        {
            float m = -INFINITY;
#pragma unroll
            for (int k = 0; k < 8; k++)
                m = fmaxf(m, p1[(size_t)(g * 8 + k) * NCOLS + j]);
            smA[t] = m;
            __syncthreads();
            if (g == 0) {
#pragma unroll
                for (int gg = 1; gg < 32; gg++) m = fmaxf(m, smA[gg * 16 + c]);
                rot[j] = m * onel_own;
            }
        }
        gbar(bar, base + 1);

        // ---- P2: ro_max + g_theta + y update + dual-partials (+final dual) ----
        {
            const float4* v4 = reinterpret_cast<const float4*>(rot);
            float4 vA = v4[2 * t];
            float4 vB = v4[2 * t + 1];
            float vv[8] = {vA.x, vA.y, vA.z, vA.w, vB.x, vB.y, vB.z, vB.w};
#pragma unroll
            for (int i = 0; i < RPB; i++) {
                float a[8];
                unpack8(w[i], a);
                float m = -INFINITY;
#pragma unroll
                for (int cc = 0; cc < 8; cc++) m = fmaxf(m, a[cc] * vv[cc]);
                prt[i][t] = m;
            }
            __syncthreads();
#pragma unroll
            for (int rr = 0; rr < 2; rr++) {
                int row = wid * 2 + rr;
                float m = -INFINITY;
#pragma unroll
                for (int k = 0; k < 8; k++) m = fmaxf(m, prt[row][lane + 64 * k]);
                m = waveMax(m);  // broadcast
                float oR = s_oner[row];
                float roi = s_ro[row];
                float z = roi - m * oR * 0.5f;  // ro - ro_max/ALPHA
                float term = 0.f;
                if (lane < 16)
                    term = tg[3 * lane] * sigf(tg[3 * lane + 1] * z + tg[3 * lane + 2]);
                float gv = waveSum(term);
                float yd = gv * oR;
                if (lane == 0) {
                    float yn = (s_y[row] + yd) * oR;
                    s_y[row] = yn;
                    s_ydl[row] = yd;
                    s_ydrol[row] = yd / roi;
                }
            }
            if (fin) {  // pred_dual rides on the registers we already hold
                float hv[8];
                const float4* h4 = reinterpret_cast<const float4*>(hwv);
                float4 hA = h4[2 * t];
                float4 hB = h4[2 * t + 1];
                hv[0] = hA.x; hv[1] = hA.y; hv[2] = hA.z; hv[3] = hA.w;
                hv[4] = hB.x; hv[5] = hB.y; hv[6] = hB.z; hv[7] = hB.w;
                __syncthreads();
#pragma unroll
                for (int i = 0; i < RPB; i++) {
                    float a[8];
                    unpack8(w[i], a);
                    float d = 0.f;
#pragma unroll
                    for (int cc = 0; cc < 8; cc++) d += a[cc] * hv[cc];
                    prt[i][t] = d;
                }
                __syncthreads();
#pragma unroll
                for (int rr = 0; rr < 2; rr++) {
                    int row = wid * 2 + rr;
                    float dd = 0.f;
#pragma unroll
                    for (int k = 0; k < 8; k++) dd += prt[row][lane + 64 * k];
                    dd = waveSum(dd);
                    if (lane == 0)
                        out[NCOLS + r0 + row] = s_y[row] + s_rm[row] + dd;
                }
            }
            __syncthreads();
            float s1[8], s2[8];
#pragma unroll
            for (int cc = 0; cc < 8; cc++) { s1[cc] = 0.f; s2[cc] = 0.f; }
#pragma unroll
            for (int i = 0; i < RPB; i++) {
                float a[8];
                unpack8(w[i], a);
                float u = s_ydl[i];
                float q = s_ydrol[i];
#pragma unroll
                for (int cc = 0; cc < 8; cc++) {
                    s1[cc] += a[cc] * u;
                    s2[cc] += a[cc] * q;
                }
            }
            float4* q1 = reinterpret_cast<float4*>(p1 + (size_t)s * NCOLS + 8 * t);
            float4* q2 = reinterpret_cast<float4*>(p2 + (size_t)s * NCOLS + 8 * t);
            q1[0] = make_float4(s1[0], s1[1], s1[2], s1[3]);
            q1[1] = make_float4(s1[4], s1[5], s1[6], s1[7]);
            q2[0] = make_float4(s2[0], s2[1], s2[2], s2[3]);
            q2[1] = make_float4(s2[4], s2[5], s2[6], s2[7]);
        }
        gbar(bar, base + 2);

        // ---- S2: epilogue (r, x, b updates) in owner-thread registers ----
        {
            float s1 = 0.f, s2 = 0.f;
#pragma unroll
            for (int k = 0; k < 8; k++) {
                int sp = g * 8 + k;
                s1 += p1[(size_t)sp * NCOLS + j];
                s2 += p2[(size_t)sp * NCOLS + j];
            }
            smA[t] = s1;
            smB[t] = s2;
            __syncthreads();
            if (g == 0) {
#pragma unroll
                for (int gg = 1; gg < 32; gg++) {
                    s1 += smA[gg * 16 + c];
                    s2 += smB[gg * 16 + c];
                }
                float oL = onel_own;
                float rj = (r_own - fmaxf(s1, 0.f)) * oL;
                float xj = (x_own + b_own * s2) * oL;
                float fv = fptr[0];
                float bb = 0.f;
#pragma unroll
                for (int k = 0; k < 16; k++) {
                    float ak = tb[4 * k], bk = tb[4 * k + 1], ck = tb[4 * k + 2],
                          dk = tb[4 * k + 3];
                    bb += ak * sigf(bk * rj + ck) * exp2f(-fmaxf(dk * (rj - fv), 0.f));
                }
                r_own = rj;
                x_own = xj;
                b_own = bb * oL;
                bvec[j] = b_own;
                if (fin) out[j] = xj;  // pred_primal
            }
        }
        if (!fin) gbar(bar, base + 3);
    }
}

extern "C" void kernel_launch(void* const* d_in, const int* in_sizes, int n_in,
                              void* d_out, int out_size, void* d_ws, size_t ws_size,
                              hipStream_t stream) {
    const float* A = (const float*)d_in[0];
    const float* theta_g = (const float*)d_in[1];  // (5,16,3)
    const float* theta_b = (const float*)d_in[2];  // (5,16,4)
    const float* fptr = (const float*)d_in[3];     // scalar
    const float* h = (const float*)d_in[4];        // (N,)
    const float* thql = (const float*)d_in[5];     // (4,2)
    const float* thqr = (const float*)d_in[6];     // (4,2)
    float* out = (float*)d_out;  // [0:4096]=pred_primal(x), [4096:8192]=pred_dual

    // workspace layout (floats)
    float* ws = (float*)d_ws;
    float* bvec = ws + 0 * 4096;
    float* rot = ws + 1 * 4096;
    float* hwv = ws + 2 * 4096;
    float* p1 = ws + 4 * 4096;
    float* p2 = p1 + (size_t)NBLK * NCOLS;
    unsigned* bar = (unsigned*)(p2 + (size_t)NBLK * NCOLS);  // 32 slots

    hipMemsetAsync(bar, 0, 32 * sizeof(unsigned), stream);
    k_persist<<<NBLK, TPB, 0, stream>>>(A, theta_g, theta_b, fptr, h, thql, thqr,
                                        bvec, rot, hwv, p1, p2, bar, out);
}

// Round 3
// 437.151 us; speedup vs baseline: 1.2071x; 1.2071x over previous
//
#include <hip/hip_runtime.h>
#include <math.h>

#define NCOLS 4096
#define MROWS 4096
#define NLAYERS 5
#define RPB 16                // rows per fused block
#define NSPLIT (MROWS / RPB)  // 256 column-partial splits
#define SPER (NSPLIT / 8)     // 32 splits per thread-group in stage-2

__device__ __forceinline__ float sigf(float x) { return 1.0f / (1.0f + expf(-x)); }

// bf16 (packed in 32-bit words) -> float, exact
__device__ __forceinline__ float lo16(unsigned w) { return __uint_as_float(w << 16); }
__device__ __forceinline__ float hi16(unsigned w) { return __uint_as_float(w & 0xFFFF0000u); }

// float -> bf16 bits, round-to-nearest-even (A has no NaN/Inf)
__device__ __forceinline__ unsigned f2bf(float f) {
    unsigned u = __float_as_uint(f);
    return (u + 0x7FFFu + ((u >> 16) & 1u)) >> 16;
}

__device__ __forceinline__ void unpack8(uint4 w, float* a) {
    a[0] = lo16(w.x); a[1] = hi16(w.x); a[2] = lo16(w.y); a[3] = hi16(w.y);
    a[4] = lo16(w.z); a[5] = hi16(w.z); a[6] = lo16(w.w); a[7] = hi16(w.w);
}

// sortable-uint encoding of float: enc monotone increasing, exact inverse.
// enc(-inf)=0x007FFFFF > 0, so memset-0 is a valid "below everything" init.
__device__ __forceinline__ unsigned encf(float f) {
    unsigned u = __float_as_uint(f);
    return (u >> 31) ? ~u : (u | 0x80000000u);
}
__device__ __forceinline__ float decf(unsigned e) {
    unsigned u = (e >> 31) ? (e & 0x7FFFFFFFu) : ~e;
    return __uint_as_float(u);
}

// butterfly reductions, result broadcast to all 64 lanes
__device__ __forceinline__ float waveSum(float v) {
#pragma unroll
    for (int o = 32; o; o >>= 1) v += __shfl_xor(v, o, 64);
    return v;
}
__device__ __forceinline__ float waveMax(float v) {
#pragma unroll
    for (int o = 32; o; o >>= 1) v = fmaxf(v, __shfl_xor(v, o, 64));
    return v;
}

// ============ fused preamble: fp32 read, bf16 convert+store, rowsum->right_mask,
// ============ colsum partial p1, colmax(rm) partial p2 — ONE pass over fp32 A
__global__ __launch_bounds__(512) void k_pre_fused(
    const float* __restrict__ A, unsigned* __restrict__ Abf,
    const float* __restrict__ thqr, float* __restrict__ right_mask,
    float* __restrict__ one_r, float* __restrict__ y, float* __restrict__ p1,
    float* __restrict__ p2) {
    __shared__ float prt[RPB][512];
    __shared__ float rml[RPB];
    int t = threadIdx.x, s = blockIdx.x, r0 = s * RPB;
    int wid = t >> 6, lane = t & 63;
    const float4* a4 = reinterpret_cast<const float4*>(A);
    uint4* o4 = reinterpret_cast<uint4*>(Abf);
    uint4 w[RPB];
#pragma unroll
    for (int i = 0; i < RPB; i++) {
        size_t base = (size_t)(r0 + i) * 1024 + 2 * t;
        float4 fA = a4[base];
        float4 fB = a4[base + 1];
        prt[i][t] = ((fA.x + fA.y) + (fA.z + fA.w)) + ((fB.x + fB.y) + (fB.z + fB.w));
        uint4 u;
        u.x = f2bf(fA.x) | (f2bf(fA.y) << 16);
        u.y = f2bf(fA.z) | (f2bf(fA.w) << 16);
        u.z = f2bf(fB.x) | (f2bf(fB.y) << 16);
        u.w = f2bf(fB.z) | (f2bf(fB.w) << 16);
        w[i] = u;
        o4[(size_t)(r0 + i) * 512 + t] = u;
    }
    __syncthreads();
#pragma unroll
    for (int rr = 0; rr < 2; rr++) {  // 2 rows per wave: rowsum -> right_mask
        int row = wid * 2 + rr;
        float sv = 0.f;
#pragma unroll
        for (int k = 0; k < 8; k++) sv += prt[row][lane + 64 * k];
        sv = waveSum(sv);
        if (lane == 0) {
            float q = 0.f;
#pragma unroll
            for (int k = 0; k < 4; k++) q += sigf(thqr[2 * k] * sv + thqr[2 * k + 1]);
            float rmv = q * 0.25f;
            right_mask[r0 + row] = rmv;
            one_r[r0 + row] = 1.0f - rmv;
            y[r0 + row] = 0.f;
            rml[row] = rmv;
        }
    }
    __syncthreads();
    float cs[8], cm[8];
#pragma unroll
    for (int c = 0; c < 8; c++) { cs[c] = 0.f; cm[c] = -INFINITY; }
#pragma unroll
    for (int i = 0; i < RPB; i++) {
        float a[8];
        unpack8(w[i], a);
        float vi = rml[i];
#pragma unroll
        for (int c = 0; c < 8; c++) {
            cs[c] += a[c];
            cm[c] = fmaxf(cm[c], a[c] * vi);
        }
    }
    float4* q1 = reinterpret_cast<float4*>(p1 + (size_t)s * NCOLS + 8 * t);
    float4* q2 = reinterpret_cast<float4*>(p2 + (size_t)s * NCOLS + 8 * t);
    q1[0] = make_float4(cs[0], cs[1], cs[2], cs[3]);
    q1[1] = make_float4(cs[4], cs[5], cs[6], cs[7]);
    q2[0] = make_float4(cm[0], cm[1], cm[2], cm[3]);
    q2[1] = make_float4(cm[4], cm[5], cm[6], cm[7]);
}

// ============ fused: ro[i]=(A@b)*one_r  +  colmax via atomicMax(enc) — ONE pass,
// ============ no partial array, no k_rot kernel.
__global__ __launch_bounds__(512) void k_ro_colmax(const unsigned* __restrict__ Abf,
                                                   const float* __restrict__ bvec,
                                                   const float* __restrict__ one_r,
                                                   float* __restrict__ ro,
                                                   unsigned* __restrict__ rot_u) {
    __shared__ float prt[RPB][512];
    __shared__ float rol[RPB];
    int t = threadIdx.x, s = blockIdx.x, r0 = s * RPB;
    int wid = t >> 6, lane = t & 63;
    const uint4* a8 = reinterpret_cast<const uint4*>(Abf);
    const float4* b4 = reinterpret_cast<const float4*>(bvec);
    float4 bA = b4[2 * t];
    float4 bB = b4[2 * t + 1];
    float bb[8] = {bA.x, bA.y, bA.z, bA.w, bB.x, bB.y, bB.z, bB.w};
    uint4 w[RPB];
#pragma unroll
    for (int i = 0; i < RPB; i++) w[i] = a8[(size_t)(r0 + i) * 512 + t];
#pragma unroll
    for (int i = 0; i < RPB; i++) {
        float a[8];
        unpack8(w[i], a);
        float d = 0.f;
#pragma unroll
        for (int c = 0; c < 8; c++) d += a[c] * bb[c];
        prt[i][t] = d;
    }
    __syncthreads();
#pragma unroll
    for (int rr = 0; rr < 2; rr++) {
        int row = wid * 2 + rr;
        float sv = 0.f;
#pragma unroll
        for (int k = 0; k < 8; k++) sv += prt[row][lane + 64 * k];
        sv = waveSum(sv);
        if (lane == 0) {
            float rv = sv * one_r[r0 + row];
            ro[r0 + row] = rv;
            rol[row] = rv;
        }
    }
    __syncthreads();
    float cm[8];
#pragma unroll
    for (int c = 0; c < 8; c++) cm[c] = -INFINITY;
#pragma unroll
    for (int i = 0; i < RPB; i++) {
        float a[8];
        unpack8(w[i], a);
        float vi = rol[i];
#pragma unroll
        for (int c = 0; c < 8; c++) cm[c] = fmaxf(cm[c], a[c] * vi);
    }
    unsigned* ru = rot_u + 8 * t;
#pragma unroll
    for (int c = 0; c < 8; c++) atomicMax(&ru[c], encf(cm[c]));
}

// ============ fused: row max-product + g_theta + y update + dual partials — ONE pass
// rot comes in encoded; one_l applied at decode (max commutes with positive scale).
// FINAL=1 additionally computes pred_dual[row] = y_final + right_mask + A@hw.
template <int FINAL>
__global__ __launch_bounds__(512) void k_row_dual(
    const unsigned* __restrict__ Abf, const unsigned* __restrict__ rot_u,
    const float* __restrict__ one_l, const float* __restrict__ one_r,
    const float* __restrict__ ro, const float* __restrict__ tg,
    float* __restrict__ y, float* __restrict__ p1, float* __restrict__ p2,
    const float* __restrict__ hwv, const float* __restrict__ rm,
    float* __restrict__ out) {
    __shared__ float prt[RPB][512];
    __shared__ float prt2[FINAL ? RPB : 1][512];
    __shared__ float ydl[RPB];
    __shared__ float ydrol[RPB];
    int t = threadIdx.x, s = blockIdx.x, r0 = s * RPB;
    int wid = t >> 6, lane = t & 63;
    const uint4* a8 = reinterpret_cast<const uint4*>(Abf);
    const uint4* r4 = reinterpret_cast<const uint4*>(rot_u);
    const float4* o4 = reinterpret_cast<const float4*>(one_l);
    uint4 rA = r4[2 * t], rB = r4[2 * t + 1];
    float4 oA = o4[2 * t], oB = o4[2 * t + 1];
    float vv[8] = {decf(rA.x) * oA.x, decf(rA.y) * oA.y, decf(rA.z) * oA.z,
                   decf(rA.w) * oA.w, decf(rB.x) * oB.x, decf(rB.y) * oB.y,
                   decf(rB.z) * oB.z, decf(rB.w) * oB.w};
    float hv[8];
    if (FINAL) {
        const float4* h4 = reinterpret_cast<const float4*>(hwv);
        float4 hA = h4[2 * t];
        float4 hB = h4[2 * t + 1];
        hv[0] = hA.x; hv[1] = hA.y; hv[2] = hA.z; hv[3] = hA.w;
        hv[4] = hB.x; hv[5] = hB.y; hv[6] = hB.z; hv[7] = hB.w;
    }
    uint4 w[RPB];
#pragma unroll
    for (int i = 0; i < RPB; i++) w[i] = a8[(size_t)(r0 + i) * 512 + t];
#pragma unroll
    for (int i = 0; i < RPB; i++) {
        float a[8];
        unpack8(w[i], a);
        float m = -INFINITY;
#pragma unroll
        for (int c = 0; c < 8; c++) m = fmaxf(m, a[c] * vv[c]);
        prt[i][t] = m;
        if (FINAL) {
            float d = 0.f;
#pragma unroll
            for (int c = 0; c < 8; c++) d += a[c] * hv[c];
            prt2[i][t] = d;
        }
    }
    __syncthreads();
#pragma unroll
    for (int rr = 0; rr < 2; rr++) {
        int row = wid * 2 + rr;
        float m = -INFINITY;
#pragma unroll
        for (int k = 0; k < 8; k++) m = fmaxf(m, prt[row][lane + 64 * k]);
        m = waveMax(m);  // broadcast
        float dd = 0.f;
        if (FINAL) {
#pragma unroll
            for (int k = 0; k < 8; k++) dd += prt2[row][lane + 64 * k];
            dd = waveSum(dd);
        }
        float oR = one_r[r0 + row];
        float roi = ro[r0 + row];
        float z = roi - m * oR * 0.5f;  // ro - ro_max/ALPHA
        float term = 0.f;
        if (lane < 16)
            term = tg[3 * lane] * sigf(tg[3 * lane + 1] * z + tg[3 * lane + 2]);
        float g = waveSum(term);
        float yd = g * oR;
        if (lane == 0) {
            float yn = (y[r0 + row] + yd) * oR;
            y[r0 + row] = yn;
            ydl[row] = yd;
            ydrol[row] = yd / roi;
            if (FINAL) out[NCOLS + r0 + row] = yn + rm[r0 + row] + dd;  // pred_dual
        }
    }
    __syncthreads();
    float s1[8], s2[8];
#pragma unroll
    for (int c = 0; c < 8; c++) { s1[c] = 0.f; s2[c] = 0.f; }
#pragma unroll
    for (int i = 0; i < RPB; i++) {
        float a[8];
        unpack8(w[i], a);
        float u = ydl[i];
        float q = ydrol[i];
#pragma unroll
        for (int c = 0; c < 8; c++) {
            s1[c] += a[c] * u;
            s2[c] += a[c] * q;
        }
    }
    float4* q1 = reinterpret_cast<float4*>(p1 + (size_t)s * NCOLS + 8 * t);
    float4* q2 = reinterpret_cast<float4*>(p2 + (size_t)s * NCOLS + 8 * t);
    q1[0] = make_float4(s1[0], s1[1], s1[2], s1[3]);
    q1[1] = make_float4(s1[4], s1[5], s1[6], s1[7]);
    q2[0] = make_float4(s2[0], s2[1], s2[2], s2[3]);
    q2[1] = make_float4(s2[4], s2[5], s2[6], s2[7]);
}

// ---------------- stage-2 reductions (parallel over splits) ----------------
// 128 blocks x 256 threads; 32 columns/block; 8 groups x SPER splits.

__global__ __launch_bounds__(256) void k_left(const float* __restrict__ p1,
                                              const float* __restrict__ p2,
                                              const float* __restrict__ thql,
                                              const float* __restrict__ h,
                                              const float* __restrict__ fptr,
                                              float* __restrict__ one_l,
                                              float* __restrict__ hw,
                                              float* __restrict__ r,
                                              float* __restrict__ b,
                                              float* __restrict__ x,
                                              unsigned* __restrict__ rot_u) {
    __shared__ float smS[256];
    __shared__ float smM[256];
    int gid = blockIdx.x * 256 + threadIdx.x;
    if (gid < NCOLS) rot_u[gid] = 0u;  // init encoded-colmax for layer 0
    int jl = threadIdx.x & 31;
    int g = threadIdx.x >> 5;  // 0..7
    int j = blockIdx.x * 32 + jl;
    float cs = 0.f, cm = -INFINITY;
#pragma unroll
    for (int t = 0; t < SPER; t++) {
        int s = g * SPER + t;
        cs += p1[(size_t)s * NCOLS + j];
        cm = fmaxf(cm, p2[(size_t)s * NCOLS + j]);
    }
    smS[threadIdx.x] = cs;
    smM[threadIdx.x] = cm;
    __syncthreads();
    if (g == 0) {
#pragma unroll
        for (int gg = 1; gg < 8; gg++) {
            cs += smS[gg * 32 + jl];
            cm = fmaxf(cm, smM[gg * 32 + jl]);
        }
        float q = 0.f;
#pragma unroll
        for (int k = 0; k < 4; k++) q += sigf(thql[2 * k] * cs + thql[2 * k + 1]);
        float c1 = q * 0.25f;
        float lm = fmaxf(c1, cm);
        one_l[j] = 1.0f - lm;
        hw[j] = h[j] * lm / cs;
        r[j] = fptr[0];
        b[j] = 1.0f;
        x[j] = 0.f;
    }
}

__global__ __launch_bounds__(256) void k_epilogue(
    const float* __restrict__ p1, const float* __restrict__ p2,
    const float* __restrict__ one_l, const float* __restrict__ tb,
    const float* __restrict__ fptr, float* __restrict__ r, float* __restrict__ b,
    float* __restrict__ x, unsigned* __restrict__ rot_u, float* __restrict__ out,
    int last) {
    __shared__ float smA[256];
    __shared__ float smB[256];
    int gid = blockIdx.x * 256 + threadIdx.x;
    if (gid < NCOLS) rot_u[gid] = 0u;  // re-init encoded-colmax for next layer
    int jl = threadIdx.x & 31;
    int g = threadIdx.x >> 5;
    int j = blockIdx.x * 32 + jl;
    float s1 = 0.f, s2 = 0.f;
#pragma unroll
    for (int t = 0; t < SPER; t++) {
        int s = g * SPER + t;
        s1 += p1[(size_t)s * NCOLS + j];
        s2 += p2[(size_t)s * NCOLS + j];
    }
    smA[threadIdx.x] = s1;
    smB[threadIdx.x] = s2;
    __syncthreads();
    if (g == 0) {
#pragma unroll
        for (int gg = 1; gg < 8; gg++) {
            s1 += smA[gg * 32 + jl];
            s2 += smB[gg * 32 + jl];
        }
        float oL = one_l[j];
        float rj = (r[j] - fmaxf(s1, 0.f)) * oL;
        float xj = (x[j] + b[j] * s2) * oL;
        float fv = fptr[0];
        float bb = 0.f;
#pragma unroll
        for (int k = 0; k < 16; k++) {
            float ak = tb[4 * k], bk = tb[4 * k + 1], ck = tb[4 * k + 2],
                  dk = tb[4 * k + 3];
            bb += ak * sigf(bk * rj + ck) * exp2f(-fmaxf(dk * (rj - fv), 0.f));
        }
        r[j] = rj;
        x[j] = xj;
        if (last) out[j] = xj;  // pred_primal
        b[j] = bb * oL;
    }
}

extern "C" void kernel_launch(void* const* d_in, const int* in_sizes, int n_in,
                              void* d_out, int out_size, void* d_ws, size_t ws_size,
                              hipStream_t stream) {
    const float* A = (const float*)d_in[0];
    const float* theta_g = (const float*)d_in[1];  // (5,16,3)
    const float* theta_b = (const float*)d_in[2];  // (5,16,4)
    const float* fptr = (const float*)d_in[3];     // scalar
    const float* h = (const float*)d_in[4];        // (N,)
    const float* thql = (const float*)d_in[5];     // (4,2)
    const float* thqr = (const float*)d_in[6];     // (4,2)
    float* out = (float*)d_out;  // [0:4096]=pred_primal(x), [4096:8192]=pred_dual

    // workspace layout (floats)
    float* ws = (float*)d_ws;
    float* right_mask = ws + 0 * 4096;
    float* one_r = ws + 1 * 4096;
    float* one_l = ws + 2 * 4096;
    float* hwv = ws + 3 * 4096;
    float* ro = ws + 4 * 4096;
    float* r = ws + 6 * 4096;
    float* b = ws + 7 * 4096;
    float* x = ws + 8 * 4096;
    float* y = ws + 9 * 4096;
    unsigned* rot_u = (unsigned*)(ws + 10 * 4096);  // encoded colmax, 16 KB
    float* p1 = ws + 12 * 4096;
    float* p2 = p1 + (size_t)NSPLIT * NCOLS;
    unsigned* Abf = (unsigned*)(p2 + (size_t)NSPLIT * NCOLS);  // 32 MB bf16 copy

    // preamble: ONE pass over fp32 A (convert + rowsum/right_mask + col partials)
    k_pre_fused<<<NSPLIT, 512, 0, stream>>>(A, Abf, thqr, right_mask, one_r, y, p1, p2);
    k_left<<<128, 256, 0, stream>>>(p1, p2, thql, h, fptr, one_l, hwv, r, b, x, rot_u);

    // layers: 3 dispatches each (k_rot eliminated via encoded atomicMax)
    for (int l = 0; l < NLAYERS; l++) {
        k_ro_colmax<<<NSPLIT, 512, 0, stream>>>(Abf, b, one_r, ro, rot_u);
        if (l < NLAYERS - 1)
            k_row_dual<0><<<NSPLIT, 512, 0, stream>>>(Abf, rot_u, one_l, one_r, ro,
                                                      theta_g + l * 48, y, p1, p2, hwv,
                                                      right_mask, out);
        else
            k_row_dual<1><<<NSPLIT, 512, 0, stream>>>(Abf, rot_u, one_l, one_r, ro,
                                                      theta_g + l * 48, y, p1, p2, hwv,
                                                      right_mask, out);
        k_epilogue<<<128, 256, 0, stream>>>(p1, p2, one_l, theta_b + l * 64, fptr, r, b,
                                            x, rot_u, out, l == NLAYERS - 1);
    }
}

// Round 4
// 231.417 us; speedup vs baseline: 2.2803x; 1.8890x over previous
//
#include <hip/hip_runtime.h>
#include <math.h>

#define NCOLS 4096
#define MROWS 4096
#define NLAYERS 5
#define RPB 16                // rows per fused block
#define NSPLIT (MROWS / RPB)  // 256 column-partial splits
#define SPER (NSPLIT / 8)     // 32 splits per thread-group in stage-2

__device__ __forceinline__ float sigf(float x) { return 1.0f / (1.0f + expf(-x)); }

// bf16 (packed in 32-bit words) -> float, exact
__device__ __forceinline__ float lo16(unsigned w) { return __uint_as_float(w << 16); }
__device__ __forceinline__ float hi16(unsigned w) { return __uint_as_float(w & 0xFFFF0000u); }

// float -> bf16 bits, round-to-nearest-even (A has no NaN/Inf)
__device__ __forceinline__ unsigned f2bf(float f) {
    unsigned u = __float_as_uint(f);
    return (u + 0x7FFFu + ((u >> 16) & 1u)) >> 16;
}

__device__ __forceinline__ void unpack8(uint4 w, float* a) {
    a[0] = lo16(w.x); a[1] = hi16(w.x); a[2] = lo16(w.y); a[3] = hi16(w.y);
    a[4] = lo16(w.z); a[5] = hi16(w.z); a[6] = lo16(w.w); a[7] = hi16(w.w);
}

// ---- non-temporal access: keep L2 for Abf (the only reused array) ----
typedef float __attribute__((ext_vector_type(4))) fv4;

__device__ __forceinline__ float4 ntload4f(const float* p) {
    fv4 v = __builtin_nontemporal_load(reinterpret_cast<const fv4*>(p));
    return make_float4(v.x, v.y, v.z, v.w);
}
__device__ __forceinline__ void ntstore4f(float* p, float4 v) {
    fv4 t = {v.x, v.y, v.z, v.w};
    __builtin_nontemporal_store(t, reinterpret_cast<fv4*>(p));
}
__device__ __forceinline__ float ntloadf(const float* p) {
    return __builtin_nontemporal_load(p);
}

// butterfly reductions, result broadcast to all 64 lanes
__device__ __forceinline__ float waveSum(float v) {
#pragma unroll
    for (int o = 32; o; o >>= 1) v += __shfl_xor(v, o, 64);
    return v;
}
__device__ __forceinline__ float waveMax(float v) {
#pragma unroll
    for (int o = 32; o; o >>= 1) v = fmaxf(v, __shfl_xor(v, o, 64));
    return v;
}

// ============ fused preamble: fp32 read (nt), bf16 convert+store (cached),
// ============ rowsum->right_mask, colsum partial p1, colmax(rm) partial p2
__global__ __launch_bounds__(512) void k_pre_fused(
    const float* __restrict__ A, unsigned* __restrict__ Abf,
    const float* __restrict__ thqr, float* __restrict__ right_mask,
    float* __restrict__ one_r, float* __restrict__ y, float* __restrict__ p1,
    float* __restrict__ p2) {
    __shared__ float prt[RPB][512];
    __shared__ float rml[RPB];
    int t = threadIdx.x, s = blockIdx.x, r0 = s * RPB;
    int wid = t >> 6, lane = t & 63;
    uint4* o4 = reinterpret_cast<uint4*>(Abf);
    uint4 w[RPB];
#pragma unroll
    for (int i = 0; i < RPB; i++) {
        const float* ap = A + (size_t)(r0 + i) * NCOLS + 8 * t;
        float4 fA = ntload4f(ap);
        float4 fB = ntload4f(ap + 4);
        prt[i][t] = ((fA.x + fA.y) + (fA.z + fA.w)) + ((fB.x + fB.y) + (fB.z + fB.w));
        uint4 u;
        u.x = f2bf(fA.x) | (f2bf(fA.y) << 16);
        u.y = f2bf(fA.z) | (f2bf(fA.w) << 16);
        u.z = f2bf(fB.x) | (f2bf(fB.y) << 16);
        u.w = f2bf(fB.z) | (f2bf(fB.w) << 16);
        w[i] = u;
        o4[(size_t)(r0 + i) * 512 + t] = u;  // cached: reused 10x by layer passes
    }
    __syncthreads();
#pragma unroll
    for (int rr = 0; rr < 2; rr++) {  // 2 rows per wave: rowsum -> right_mask
        int row = wid * 2 + rr;
        float sv = 0.f;
#pragma unroll
        for (int k = 0; k < 8; k++) sv += prt[row][lane + 64 * k];
        sv = waveSum(sv);
        if (lane == 0) {
            float q = 0.f;
#pragma unroll
            for (int k = 0; k < 4; k++) q += sigf(thqr[2 * k] * sv + thqr[2 * k + 1]);
            float rmv = q * 0.25f;
            right_mask[r0 + row] = rmv;
            one_r[r0 + row] = 1.0f - rmv;
            y[r0 + row] = 0.f;
            rml[row] = rmv;
        }
    }
    __syncthreads();
    float cs[8], cm[8];
#pragma unroll
    for (int c = 0; c < 8; c++) { cs[c] = 0.f; cm[c] = -INFINITY; }
#pragma unroll
    for (int i = 0; i < RPB; i++) {
        float a[8];
        unpack8(w[i], a);
        float vi = rml[i];
#pragma unroll
        for (int c = 0; c < 8; c++) {
            cs[c] += a[c];
            cm[c] = fmaxf(cm[c], a[c] * vi);
        }
    }
    float* q1 = p1 + (size_t)s * NCOLS + 8 * t;
    float* q2 = p2 + (size_t)s * NCOLS + 8 * t;
    ntstore4f(q1, make_float4(cs[0], cs[1], cs[2], cs[3]));
    ntstore4f(q1 + 4, make_float4(cs[4], cs[5], cs[6], cs[7]));
    ntstore4f(q2, make_float4(cm[0], cm[1], cm[2], cm[3]));
    ntstore4f(q2 + 4, make_float4(cm[4], cm[5], cm[6], cm[7]));
}

// ============ fused: ro[i]=(A@b)*one_r  +  colmax partial p1 — ONE bf16 pass
__global__ __launch_bounds__(512) void k_ro_colmax(const unsigned* __restrict__ Abf,
                                                   const float* __restrict__ bvec,
                                                   const float* __restrict__ one_r,
                                                   float* __restrict__ ro,
                                                   float* __restrict__ p1) {
    __shared__ float prt[RPB][512];
    __shared__ float rol[RPB];
    int t = threadIdx.x, s = blockIdx.x, r0 = s * RPB;
    int wid = t >> 6, lane = t & 63;
    const uint4* a8 = reinterpret_cast<const uint4*>(Abf);
    const float4* b4 = reinterpret_cast<const float4*>(bvec);
    float4 bA = b4[2 * t];
    float4 bB = b4[2 * t + 1];
    float bb[8] = {bA.x, bA.y, bA.z, bA.w, bB.x, bB.y, bB.z, bB.w};
    uint4 w[RPB];
#pragma unroll
    for (int i = 0; i < RPB; i++) w[i] = a8[(size_t)(r0 + i) * 512 + t];
#pragma unroll
    for (int i = 0; i < RPB; i++) {
        float a[8];
        unpack8(w[i], a);
        float d = 0.f;
#pragma unroll
        for (int c = 0; c < 8; c++) d += a[c] * bb[c];
        prt[i][t] = d;
    }
    __syncthreads();
#pragma unroll
    for (int rr = 0; rr < 2; rr++) {
        int row = wid * 2 + rr;
        float sv = 0.f;
#pragma unroll
        for (int k = 0; k < 8; k++) sv += prt[row][lane + 64 * k];
        sv = waveSum(sv);
        if (lane == 0) {
            float rv = sv * one_r[r0 + row];
            ro[r0 + row] = rv;
            rol[row] = rv;
        }
    }
    __syncthreads();
    float cm[8];
#pragma unroll
    for (int c = 0; c < 8; c++) cm[c] = -INFINITY;
#pragma unroll
    for (int i = 0; i < RPB; i++) {
        float a[8];
        unpack8(w[i], a);
        float vi = rol[i];
#pragma unroll
        for (int c = 0; c < 8; c++) cm[c] = fmaxf(cm[c], a[c] * vi);
    }
    float* q1 = p1 + (size_t)s * NCOLS + 8 * t;
    ntstore4f(q1, make_float4(cm[0], cm[1], cm[2], cm[3]));
    ntstore4f(q1 + 4, make_float4(cm[4], cm[5], cm[6], cm[7]));
}

// ============ fused: row max-product + g_theta + y update + dual partials
// FINAL=1 additionally computes pred_dual[row] = y_final + right_mask + A@hw.
template <int FINAL>
__global__ __launch_bounds__(512) void k_row_dual(
    const unsigned* __restrict__ Abf, const float* __restrict__ ro_t,
    const float* __restrict__ one_r, const float* __restrict__ ro,
    const float* __restrict__ tg, float* __restrict__ y, float* __restrict__ p1,
    float* __restrict__ p2, const float* __restrict__ hwv,
    const float* __restrict__ rm, float* __restrict__ out) {
    __shared__ float prt[RPB][512];
    __shared__ float prt2[FINAL ? RPB : 1][512];
    __shared__ float ydl[RPB];
    __shared__ float ydrol[RPB];
    int t = threadIdx.x, s = blockIdx.x, r0 = s * RPB;
    int wid = t >> 6, lane = t & 63;
    const uint4* a8 = reinterpret_cast<const uint4*>(Abf);
    const float4* v4 = reinterpret_cast<const float4*>(ro_t);
    float4 vA = v4[2 * t];
    float4 vB = v4[2 * t + 1];
    float vv[8] = {vA.x, vA.y, vA.z, vA.w, vB.x, vB.y, vB.z, vB.w};
    float hv[8];
    if (FINAL) {
        const float4* h4 = reinterpret_cast<const float4*>(hwv);
        float4 hA = h4[2 * t];
        float4 hB = h4[2 * t + 1];
        hv[0] = hA.x; hv[1] = hA.y; hv[2] = hA.z; hv[3] = hA.w;
        hv[4] = hB.x; hv[5] = hB.y; hv[6] = hB.z; hv[7] = hB.w;
    }
    uint4 w[RPB];
#pragma unroll
    for (int i = 0; i < RPB; i++) w[i] = a8[(size_t)(r0 + i) * 512 + t];
#pragma unroll
    for (int i = 0; i < RPB; i++) {
        float a[8];
        unpack8(w[i], a);
        float m = -INFINITY;
#pragma unroll
        for (int c = 0; c < 8; c++) m = fmaxf(m, a[c] * vv[c]);
        prt[i][t] = m;
        if (FINAL) {
            float d = 0.f;
#pragma unroll
            for (int c = 0; c < 8; c++) d += a[c] * hv[c];
            prt2[i][t] = d;
        }
    }
    __syncthreads();
#pragma unroll
    for (int rr = 0; rr < 2; rr++) {
        int row = wid * 2 + rr;
        float m = -INFINITY;
#pragma unroll
        for (int k = 0; k < 8; k++) m = fmaxf(m, prt[row][lane + 64 * k]);
        m = waveMax(m);  // broadcast
        float dd = 0.f;
        if (FINAL) {
#pragma unroll
            for (int k = 0; k < 8; k++) dd += prt2[row][lane + 64 * k];
            dd = waveSum(dd);
        }
        float oR = one_r[r0 + row];
        float roi = ro[r0 + row];
        float z = roi - m * oR * 0.5f;  // ro - ro_max/ALPHA
        float term = 0.f;
        if (lane < 16)
            term = tg[3 * lane] * sigf(tg[3 * lane + 1] * z + tg[3 * lane + 2]);
        float g = waveSum(term);
        float yd = g * oR;
        if (lane == 0) {
            float yn = (y[r0 + row] + yd) * oR;
            y[r0 + row] = yn;
            ydl[row] = yd;
            ydrol[row] = yd / roi;
            if (FINAL) out[NCOLS + r0 + row] = yn + rm[r0 + row] + dd;  // pred_dual
        }
    }
    __syncthreads();
    float s1[8], s2[8];
#pragma unroll
    for (int c = 0; c < 8; c++) { s1[c] = 0.f; s2[c] = 0.f; }
#pragma unroll
    for (int i = 0; i < RPB; i++) {
        float a[8];
        unpack8(w[i], a);
        float u = ydl[i];
        float q = ydrol[i];
#pragma unroll
        for (int c = 0; c < 8; c++) {
            s1[c] += a[c] * u;
            s2[c] += a[c] * q;
        }
    }
    float* q1 = p1 + (size_t)s * NCOLS + 8 * t;
    float* q2 = p2 + (size_t)s * NCOLS + 8 * t;
    ntstore4f(q1, make_float4(s1[0], s1[1], s1[2], s1[3]));
    ntstore4f(q1 + 4, make_float4(s1[4], s1[5], s1[6], s1[7]));
    ntstore4f(q2, make_float4(s2[0], s2[1], s2[2], s2[3]));
    ntstore4f(q2 + 4, make_float4(s2[4], s2[5], s2[6], s2[7]));
}

// ---------------- stage-2 reductions (parallel over splits) ----------------
// 128 blocks x 256 threads; 32 columns/block; 8 groups x SPER splits.
// All partial reads are non-temporal (read-once streams).

__global__ __launch_bounds__(256) void k_left(const float* __restrict__ p1,
                                              const float* __restrict__ p2,
                                              const float* __restrict__ thql,
                                              const float* __restrict__ h,
                                              const float* __restrict__ fptr,
                                              float* __restrict__ one_l,
                                              float* __restrict__ hw,
                                              float* __restrict__ r,
                                              float* __restrict__ b,
                                              float* __restrict__ x) {
    __shared__ float smS[256];
    __shared__ float smM[256];
    int jl = threadIdx.x & 31;
    int g = threadIdx.x >> 5;  // 0..7
    int j = blockIdx.x * 32 + jl;
    float cs = 0.f, cm = -INFINITY;
#pragma unroll
    for (int t = 0; t < SPER; t++) {
        int s = g * SPER + t;
        cs += ntloadf(&p1[(size_t)s * NCOLS + j]);
        cm = fmaxf(cm, ntloadf(&p2[(size_t)s * NCOLS + j]));
    }
    smS[threadIdx.x] = cs;
    smM[threadIdx.x] = cm;
    __syncthreads();
    if (g == 0) {
#pragma unroll
        for (int gg = 1; gg < 8; gg++) {
            cs += smS[gg * 32 + jl];
            cm = fmaxf(cm, smM[gg * 32 + jl]);
        }
        float q = 0.f;
#pragma unroll
        for (int k = 0; k < 4; k++) q += sigf(thql[2 * k] * cs + thql[2 * k + 1]);
        float c1 = q * 0.25f;
        float lm = fmaxf(c1, cm);
        one_l[j] = 1.0f - lm;
        hw[j] = h[j] * lm / cs;
        r[j] = fptr[0];
        b[j] = 1.0f;
        x[j] = 0.f;
    }
}

__global__ __launch_bounds__(256) void k_rot(const float* __restrict__ p,
                                             const float* __restrict__ one_l,
                                             float* __restrict__ ro_t) {
    __shared__ float smM[256];
    int jl = threadIdx.x & 31;
    int g = threadIdx.x >> 5;
    int j = blockIdx.x * 32 + jl;
    float m = -INFINITY;
#pragma unroll
    for (int t = 0; t < SPER; t++) {
        int s = g * SPER + t;
        m = fmaxf(m, ntloadf(&p[(size_t)s * NCOLS + j]));
    }
    smM[threadIdx.x] = m;
    __syncthreads();
    if (g == 0) {
#pragma unroll
        for (int gg = 1; gg < 8; gg++) m = fmaxf(m, smM[gg * 32 + jl]);
        ro_t[j] = m * one_l[j];
    }
}

__global__ __launch_bounds__(256) void k_epilogue(const float* __restrict__ p1,
                                                  const float* __restrict__ p2,
                                                  const float* __restrict__ one_l,
                                                  const float* __restrict__ tb,
                                                  const float* __restrict__ fptr,
                                                  float* __restrict__ r,
                                                  float* __restrict__ b,
                                                  float* __restrict__ x,
                                                  float* __restrict__ out, int last) {
    __shared__ float smA[256];
    __shared__ float smB[256];
    int jl = threadIdx.x & 31;
    int g = threadIdx.x >> 5;
    int j = blockIdx.x * 32 + jl;
    float s1 = 0.f, s2 = 0.f;
#pragma unroll
    for (int t = 0; t < SPER; t++) {
        int s = g * SPER + t;
        s1 += ntloadf(&p1[(size_t)s * NCOLS + j]);
        s2 += ntloadf(&p2[(size_t)s * NCOLS + j]);
    }
    smA[threadIdx.x] = s1;
    smB[threadIdx.x] = s2;
    __syncthreads();
    if (g == 0) {
#pragma unroll
        for (int gg = 1; gg < 8; gg++) {
            s1 += smA[gg * 32 + jl];
            s2 += smB[gg * 32 + jl];
        }
        float oL = one_l[j];
        float rj = (r[j] - fmaxf(s1, 0.f)) * oL;
        float xj = (x[j] + b[j] * s2) * oL;
        float fv = fptr[0];
        float bb = 0.f;
#pragma unroll
        for (int k = 0; k < 16; k++) {
            float ak = tb[4 * k], bk = tb[4 * k + 1], ck = tb[4 * k + 2],
                  dk = tb[4 * k + 3];
            bb += ak * sigf(bk * rj + ck) * exp2f(-fmaxf(dk * (rj - fv), 0.f));
        }
        r[j] = rj;
        x[j] = xj;
        if (last) out[j] = xj;  // pred_primal
        b[j] = bb * oL;
    }
}

extern "C" void kernel_launch(void* const* d_in, const int* in_sizes, int n_in,
                              void* d_out, int out_size, void* d_ws, size_t ws_size,
                              hipStream_t stream) {
    const float* A = (const float*)d_in[0];
    const float* theta_g = (const float*)d_in[1];  // (5,16,3)
    const float* theta_b = (const float*)d_in[2];  // (5,16,4)
    const float* fptr = (const float*)d_in[3];     // scalar
    const float* h = (const float*)d_in[4];        // (N,)
    const float* thql = (const float*)d_in[5];     // (4,2)
    const float* thqr = (const float*)d_in[6];     // (4,2)
    float* out = (float*)d_out;  // [0:4096]=pred_primal(x), [4096:8192]=pred_dual

    // workspace layout (floats)
    float* ws = (float*)d_ws;
    float* right_mask = ws + 0 * 4096;
    float* one_r = ws + 1 * 4096;
    float* one_l = ws + 2 * 4096;
    float* hwv = ws + 3 * 4096;
    float* ro = ws + 4 * 4096;
    float* ro_t = ws + 5 * 4096;
    float* r = ws + 6 * 4096;
    float* b = ws + 7 * 4096;
    float* x = ws + 8 * 4096;
    float* y = ws + 9 * 4096;
    float* p1 = ws + 12 * 4096;
    float* p2 = p1 + (size_t)NSPLIT * NCOLS;
    unsigned* Abf = (unsigned*)(p2 + (size_t)NSPLIT * NCOLS);  // 32 MB bf16 copy

    // preamble: ONE pass over fp32 A (convert + rowsum/right_mask + col partials)
    k_pre_fused<<<NSPLIT, 512, 0, stream>>>(A, Abf, thqr, right_mask, one_r, y, p1, p2);
    k_left<<<128, 256, 0, stream>>>(p1, p2, thql, h, fptr, one_l, hwv, r, b, x);

    // layers: last k_row_dual also emits pred_dual; last epilogue emits pred_primal
    for (int l = 0; l < NLAYERS; l++) {
        k_ro_colmax<<<NSPLIT, 512, 0, stream>>>(Abf, b, one_r, ro, p1);
        k_rot<<<128, 256, 0, stream>>>(p1, one_l, ro_t);
        if (l < NLAYERS - 1)
            k_row_dual<0><<<NSPLIT, 512, 0, stream>>>(Abf, ro_t, one_r, ro,
                                                      theta_g + l * 48, y, p1, p2, hwv,
                                                      right_mask, out);
        else
            k_row_dual<1><<<NSPLIT, 512, 0, stream>>>(Abf, ro_t, one_r, ro,
                                                      theta_g + l * 48, y, p1, p2, hwv,
                                                      right_mask, out);
        k_epilogue<<<128, 256, 0, stream>>>(p1, p2, one_l, theta_b + l * 64, fptr, r, b,
                                            x, out, l == NLAYERS - 1);
    }
}